// Round 6
// baseline (1327.642 us; speedup 1.0000x reference)
//
#include <hip/hip_runtime.h>

// ---------------------------------------------------------------------------
// YOLOv2 head on MI355X (gfx950).
// conv1 3x3 (512->1024) + BN + leaky -> conv2 1x1 (1024->425) + bias -> decode
// fp16 3-term split GEMM (ah*bh + ah*bl + al*bh) for fp32-class accuracy.
// R6: occupancy fix — 2 independent blocks/CU so MFMA and LDS pipes overlap
// across blocks (R4/R5 had 1 block/CU: pipes fully serialized by barriers).
// Tile 128x256, BK=16, 4 waves, 48 KB LDS, 32x32x16 MFMA, fragment-order LDS
// chunks (1 KB = 32 rows x 16 k, lane-linear), 2 barrier-windows per K-tile,
// counted vmcnt(3).
// ---------------------------------------------------------------------------

typedef _Float16 f16;
typedef _Float16 f16x8 __attribute__((ext_vector_type(8)));
typedef _Float16 f16x4v __attribute__((ext_vector_type(4)));
typedef float    f32x16 __attribute__((ext_vector_type(16)));

__device__ __forceinline__ void gload16(const f16* g, f16* l) {
  __builtin_amdgcn_global_load_lds(
      (const __attribute__((address_space(1))) void*)g,
      (__attribute__((address_space(3))) void*)l, 16, 0, 0);
}

#define MFMA32(a, b, c) __builtin_amdgcn_mfma_f32_32x32x16_f16(a, b, c, 0, 0, 0)
#define ASM_VMCNT(N) asm volatile("s_waitcnt vmcnt(" #N ")" ::: "memory")
#define SBAR()                           \
  {                                      \
    __builtin_amdgcn_s_barrier();        \
    __builtin_amdgcn_sched_barrier(0);   \
  }

// LDS region bases (f16 elements). A regions: 2 bufs x 4 chunks x 512.
// B regions: 2 bufs x 8 chunks x 512. Chunk = 1 KB = 32 rows x 16 k,
// lane-linear (lane l holds elems [l*8, l*8+8) = row l&31, k-half l>>5).
#define R_AH 0
#define R_AL 4096
#define R_BH 8192
#define R_BL 16384
// total 24576 f16 = 48 KB

// anchors
__device__ const float c_AW[5] = {42.f, 98.f, 180.f, 300.f, 400.f};
__device__ const float c_AH_[5] = {45.f, 130.f, 260.f, 180.f, 400.f};

// ---------------------------------------------------------------------------
__global__ void prep_misc(const float* __restrict__ g, const float* __restrict__ be,
                          const float* __restrict__ mn, const float* __restrict__ vr,
                          const float* __restrict__ b2,
                          float* __restrict__ scale, float* __restrict__ shift,
                          float* __restrict__ bias) {
  int i = threadIdx.x;  // 1024 threads
  float s = g[i] / sqrtf(vr[i] + 1e-5f);
  shift[i] = be[i] - mn[i] * s;
  scale[i] = s * (1.0f / 1024.0f);
  if (i < 512) bias[i] = (i < 425) ? b2[i] : 0.f;
}

__global__ __launch_bounds__(256) void prep_w1(const float* __restrict__ w,
                                               f16* __restrict__ Ah, f16* __restrict__ Al) {
  const int co = blockIdx.x;
  const int k = blockIdx.y * 256 + threadIdx.x;  // < 4608
  const int ky = k / 1536, rem = k - ky * 1536;
  const int kx = rem >> 9, ci = rem & 511;
  float v = w[((co * 512 + ci) * 3 + ky) * 3 + kx] * 1024.f;
  f16 h = (f16)v;
  Ah[(long)co * 4608 + k] = h;
  Al[(long)co * 4608 + k] = (f16)(v - (float)h);
}

__global__ __launch_bounds__(256) void prep_w2(const float* __restrict__ w,
                                               f16* __restrict__ Ah, f16* __restrict__ Al) {
  const int co = blockIdx.x;                      // < 512
  const int ci = blockIdx.y * 256 + threadIdx.x;  // < 1024
  float v = (co < 425) ? w[co * 1024 + ci] * 1024.f : 0.f;
  f16 h = (f16)v;
  Ah[co * 1024 + ci] = h;
  Al[co * 1024 + ci] = (f16)(v - (float)h);
}

__global__ __launch_bounds__(256) void prep_feat(const float* __restrict__ f,
                                                 f16* __restrict__ fph, f16* __restrict__ fpl) {
  __shared__ float lds[256][33];
  const int y = blockIdx.x, b = blockIdx.y, t = threadIdx.x;
  const int xx = t & 31, cig = t >> 5;
  const float* src = f + ((long)b * 512) * 1024 + y * 32;

  for (int half = 0; half < 2; ++half) {
    const int cibase = half * 256;
    for (int rep = 0; rep < 32; ++rep) {
      int ci = rep * 8 + cig;
      lds[ci][xx] = src[(long)(cibase + ci) * 1024 + xx];
    }
    __syncthreads();
    const long rowbase = ((long)(b * 34) + (y + 1)) * 34 + 1;
    for (int xp = 0; xp < 32; ++xp) {
      float v = lds[t][xp];
      f16 h = (f16)v;
      long o = (rowbase + xp) * 512 + cibase + t;
      fph[o] = h;
      fpl[o] = (f16)(v - (float)h);
    }
    __syncthreads();
  }
}

// ---------------------------------------------------------------------------
// gemm1: C[1024][32768] = A1(1024x4608) * im2col(features) + BN + leaky.
// Tile 128(M)x256(N), BK=16, 4 waves (2Mx2N, per-wave 64x128 = 2x4 cells of
// 32x32), 288 K-tiles, 2 barrier-windows/K-tile, dbuf LDS 48 KB, vmcnt(3).
// grid (128 n-tiles, 8 m-tiles), block 256, 2 blocks/CU.
// ---------------------------------------------------------------------------
__global__ __launch_bounds__(256, 2) void gemm1(
    const f16* __restrict__ A1h, const f16* __restrict__ A1l,
    const f16* __restrict__ Bh, const f16* __restrict__ Bl,
    const float* __restrict__ scale, const float* __restrict__ shift,
    f16* __restrict__ xth, f16* __restrict__ xtl) {
  __shared__ __align__(16) f16 S[24576];  // 48 KB
  const int tid = threadIdx.x;
  const int l = tid & 63, w = tid >> 6;   // 4 waves
  const int wm = w >> 1, wn = w & 1;      // per-wave 64(M) x 128(N)
  const int l31 = l & 31, lh = l >> 5;
  const int nt = blockIdx.x, mt = blockIdx.y;
  const int n0 = nt * 256, co0 = mt * 128;
  const int b = n0 >> 10, y0 = (n0 & 1023) >> 5;  // 256 cols = 8 y-rows x 32 x

  // staging: wave w owns A chunk w (rows w*32..+32) and B chunks w, w+4
  // (image rows y0+w / y0+w+4, x = l&31). Lane-linear chunk fill.
  const long aS = (long)(co0 + w * 32 + l31) * 4608 + lh * 8;
  const long bS0 = ((long)(b * 34 + y0 + w) * 34 + l31) * 512 + lh * 8;
  const long bS1 = ((long)(b * 34 + y0 + w + 4) * 34 + l31) * 512 + lh * 8;
  const int lro = l * 8;

  f32x16 acc[2][4] = {};  // [mf][nf]
  f16x8 ah[2], al[2], bh[4], bl[4];

  // prologue: stage tile 0 (kt=0 -> kA=0, kB=0), full drain once
  gload16(A1h + aS, &S[R_AH + w * 512]);
  gload16(Bh + bS0, &S[R_BH + w * 512]);
  gload16(Bh + bS1, &S[R_BH + (w + 4) * 512]);
  gload16(Bl + bS0, &S[R_BL + w * 512]);
  gload16(Bl + bS1, &S[R_BL + (w + 4) * 512]);
  gload16(A1l + aS, &S[R_AL + w * 512]);
  ASM_VMCNT(0);
  SBAR();

  for (int t = 0; t < 288; ++t) {
    const int cA = (t & 1) << 11, nA = 2048 - cA;  // A buf offsets
    const int cB = (t & 1) << 12, nB = 4096 - cB;  // B buf offsets
    const int s1 = (t < 287) ? t + 1 : t;          // clamped prefetch tile
    const int ky1 = s1 / 96, r1 = s1 - ky1 * 96;
    const int kx1 = r1 >> 5, ci1 = (r1 & 31) << 4;
    const long kA = (long)s1 * 16;
    const long kB = (long)(ky1 * 34 + kx1) * 512 + ci1;

    // ---- PA: stage {Ahi,Bhi,Bhi}(t+1); read ah,bh(t); vmcnt(3); bar; hh ----
    gload16(A1h + aS + kA, &S[R_AH + nA + w * 512]);
    gload16(Bh + bS0 + kB, &S[R_BH + nB + w * 512]);
    gload16(Bh + bS1 + kB, &S[R_BH + nB + (w + 4) * 512]);
#pragma unroll
    for (int mf = 0; mf < 2; ++mf)
      ah[mf] = *(const f16x8*)&S[R_AH + cA + (wm * 2 + mf) * 512 + lro];
#pragma unroll
    for (int nf = 0; nf < 4; ++nf)
      bh[nf] = *(const f16x8*)&S[R_BH + cB + (wn * 4 + nf) * 512 + lro];
    ASM_VMCNT(3);  // drains {Blo,Blo,Alo}(t) staged in prev PB
    SBAR();
    __builtin_amdgcn_s_setprio(1);
#pragma unroll
    for (int mf = 0; mf < 2; ++mf)
#pragma unroll
      for (int nf = 0; nf < 4; ++nf)
        acc[mf][nf] = MFMA32(ah[mf], bh[nf], acc[mf][nf]);
    __builtin_amdgcn_s_setprio(0);

    // ---- PB: stage {Blo,Blo,Alo}(t+1); read bl,al(t); hl+lh; vmcnt(3); bar --
    gload16(Bl + bS0 + kB, &S[R_BL + nB + w * 512]);
    gload16(Bl + bS1 + kB, &S[R_BL + nB + (w + 4) * 512]);
    gload16(A1l + aS + kA, &S[R_AL + nA + w * 512]);
#pragma unroll
    for (int nf = 0; nf < 4; ++nf)
      bl[nf] = *(const f16x8*)&S[R_BL + cB + (wn * 4 + nf) * 512 + lro];
#pragma unroll
    for (int mf = 0; mf < 2; ++mf)
      al[mf] = *(const f16x8*)&S[R_AL + cA + (wm * 2 + mf) * 512 + lro];
    __builtin_amdgcn_s_setprio(1);
#pragma unroll
    for (int mf = 0; mf < 2; ++mf)
#pragma unroll
      for (int nf = 0; nf < 4; ++nf) {
        acc[mf][nf] = MFMA32(ah[mf], bl[nf], acc[mf][nf]);
        acc[mf][nf] = MFMA32(al[mf], bh[nf], acc[mf][nf]);
      }
    __builtin_amdgcn_s_setprio(0);
    ASM_VMCNT(3);  // drains {Ahi,Bhi,Bhi}(t+1) for next PA's reads
    SBAR();
  }

  // epilogue: BN (1/1024 folded) + leaky, split to fp16 hi/lo, store NHWC.
  // 32x32 C/D: col = lane&31, row = (reg&3) + 8*(reg>>2) + 4*(lane>>5)
#pragma unroll
  for (int mf = 0; mf < 2; ++mf) {
#pragma unroll
    for (int nf = 0; nf < 4; ++nf) {
      const int colB = n0 + wn * 128 + nf * 32 + l31;
      const long colOff = (long)colB * 1024;
#pragma unroll
      for (int rg = 0; rg < 4; ++rg) {
        const int cob = co0 + wm * 64 + mf * 32 + rg * 8 + lh * 4;
        const float4 scv = *(const float4*)(scale + cob);
        const float4 shv = *(const float4*)(shift + cob);
        float v0 = acc[mf][nf][rg * 4 + 0] * scv.x + shv.x; v0 = v0 > 0.f ? v0 : 0.1f * v0;
        float v1 = acc[mf][nf][rg * 4 + 1] * scv.y + shv.y; v1 = v1 > 0.f ? v1 : 0.1f * v1;
        float v2 = acc[mf][nf][rg * 4 + 2] * scv.z + shv.z; v2 = v2 > 0.f ? v2 : 0.1f * v2;
        float v3 = acc[mf][nf][rg * 4 + 3] * scv.w + shv.w; v3 = v3 > 0.f ? v3 : 0.1f * v3;
        f16 h0 = (f16)v0, h1 = (f16)v1, h2 = (f16)v2, h3 = (f16)v3;
        f16x4v hv = {h0, h1, h2, h3};
        f16x4v lv = {(f16)(v0 - (float)h0), (f16)(v1 - (float)h1),
                     (f16)(v2 - (float)h2), (f16)(v3 - (float)h3)};
        *(f16x4v*)(xth + colOff + cob) = hv;
        *(f16x4v*)(xtl + colOff + cob) = lv;
      }
    }
  }
}

// ---------------------------------------------------------------------------
// gemm2: preds[n][512] = A2(512x1024) * xt (+bias, /1024). Same structure.
// grid (128 n-tiles, 4 m-tiles), block 256. 64 K-tiles.
// ---------------------------------------------------------------------------
__global__ __launch_bounds__(256, 2) void gemm2(
    const f16* __restrict__ A2h, const f16* __restrict__ A2l,
    const f16* __restrict__ Bh, const f16* __restrict__ Bl,
    const float* __restrict__ bias, float* __restrict__ preds) {
  __shared__ __align__(16) f16 S[24576];
  const int tid = threadIdx.x;
  const int l = tid & 63, w = tid >> 6;
  const int wm = w >> 1, wn = w & 1;
  const int l31 = l & 31, lh = l >> 5;
  const int nt = blockIdx.x, mt = blockIdx.y;
  const int n0 = nt * 256, co0 = mt * 128;

  const long aS = (long)(co0 + w * 32 + l31) * 1024 + lh * 8;
  const long bS0 = (long)(n0 + w * 32 + l31) * 1024 + lh * 8;
  const long bS1 = (long)(n0 + (w + 4) * 32 + l31) * 1024 + lh * 8;
  const int lro = l * 8;

  f32x16 acc[2][4] = {};
  f16x8 ah[2], al[2], bh[4], bl[4];

  gload16(A2h + aS, &S[R_AH + w * 512]);
  gload16(Bh + bS0, &S[R_BH + w * 512]);
  gload16(Bh + bS1, &S[R_BH + (w + 4) * 512]);
  gload16(Bl + bS0, &S[R_BL + w * 512]);
  gload16(Bl + bS1, &S[R_BL + (w + 4) * 512]);
  gload16(A2l + aS, &S[R_AL + w * 512]);
  ASM_VMCNT(0);
  SBAR();

  for (int t = 0; t < 64; ++t) {
    const int cA = (t & 1) << 11, nA = 2048 - cA;
    const int cB = (t & 1) << 12, nB = 4096 - cB;
    const long kk = (long)((t < 63) ? t + 1 : t) * 16;

    // ---- PA ----
    gload16(A2h + aS + kk, &S[R_AH + nA + w * 512]);
    gload16(Bh + bS0 + kk, &S[R_BH + nB + w * 512]);
    gload16(Bh + bS1 + kk, &S[R_BH + nB + (w + 4) * 512]);
#pragma unroll
    for (int mf = 0; mf < 2; ++mf)
      ah[mf] = *(const f16x8*)&S[R_AH + cA + (wm * 2 + mf) * 512 + lro];
#pragma unroll
    for (int nf = 0; nf < 4; ++nf)
      bh[nf] = *(const f16x8*)&S[R_BH + cB + (wn * 4 + nf) * 512 + lro];
    ASM_VMCNT(3);
    SBAR();
    __builtin_amdgcn_s_setprio(1);
#pragma unroll
    for (int mf = 0; mf < 2; ++mf)
#pragma unroll
      for (int nf = 0; nf < 4; ++nf)
        acc[mf][nf] = MFMA32(ah[mf], bh[nf], acc[mf][nf]);
    __builtin_amdgcn_s_setprio(0);

    // ---- PB ----
    gload16(Bl + bS0 + kk, &S[R_BL + nB + w * 512]);
    gload16(Bl + bS1 + kk, &S[R_BL + nB + (w + 4) * 512]);
    gload16(A2l + aS + kk, &S[R_AL + nA + w * 512]);
#pragma unroll
    for (int nf = 0; nf < 4; ++nf)
      bl[nf] = *(const f16x8*)&S[R_BL + cB + (wn * 4 + nf) * 512 + lro];
#pragma unroll
    for (int mf = 0; mf < 2; ++mf)
      al[mf] = *(const f16x8*)&S[R_AL + cA + (wm * 2 + mf) * 512 + lro];
    __builtin_amdgcn_s_setprio(1);
#pragma unroll
    for (int mf = 0; mf < 2; ++mf)
#pragma unroll
      for (int nf = 0; nf < 4; ++nf) {
        acc[mf][nf] = MFMA32(ah[mf], bl[nf], acc[mf][nf]);
        acc[mf][nf] = MFMA32(al[mf], bh[nf], acc[mf][nf]);
      }
    __builtin_amdgcn_s_setprio(0);
    ASM_VMCNT(3);
    SBAR();
  }

#pragma unroll
  for (int mf = 0; mf < 2; ++mf) {
#pragma unroll
    for (int nf = 0; nf < 4; ++nf) {
      const int colB = n0 + wn * 128 + nf * 32 + l31;
      const long colOff = (long)colB * 512;
#pragma unroll
      for (int rg = 0; rg < 4; ++rg) {
        const int cob = co0 + wm * 64 + mf * 32 + rg * 8 + lh * 4;
        const float4 bi = *(const float4*)(bias + cob);
        float4 o;
        o.x = acc[mf][nf][rg * 4 + 0] * 9.765625e-4f + bi.x;
        o.y = acc[mf][nf][rg * 4 + 1] * 9.765625e-4f + bi.y;
        o.z = acc[mf][nf][rg * 4 + 2] * 9.765625e-4f + bi.z;
        o.w = acc[mf][nf][rg * 4 + 3] * 9.765625e-4f + bi.w;
        *(float4*)(preds + colOff + cob) = o;
      }
    }
  }
}

// ---------------------------------------------------------------------------
__global__ __launch_bounds__(256) void decode(const float* __restrict__ preds,
                                              float* __restrict__ out) {
  const int t = blockIdx.x * 256 + threadIdx.x;  // < 163840
  const int b = t / 5120, rem = t % 5120, pos = rem / 5, a = rem % 5;
  const int n = (b << 10) + pos;
  const float* p = preds + (long)n * 512 + a * 85;

  float tx = p[0], ty = p[1], tw = p[2], th = p[3], to = p[4];
  float mx = p[5];
  int arg = 0;
  for (int i = 1; i < 80; ++i) {
    float v = p[5 + i];
    if (v > mx) { mx = v; arg = i; }
  }
  float sum = 0.f;
  for (int i = 0; i < 80; ++i) sum += expf(p[5 + i] - mx);

  float obj = 1.f / (1.f + expf(-to));
  float score = obj / sum;
  float bx = 1.f / (1.f + expf(-tx));
  float by = 1.f / (1.f + expf(-ty));
  float bw = expf(fminf(tw, 8.f));
  float bh2 = expf(fminf(th, 8.f));
  float cx = (bx + (float)(pos & 31)) * 32.f;
  float cy = (by + (float)(pos >> 5)) * 32.f;
  float pw = c_AW[a] * bw;
  float ph = c_AH_[a] * bh2;
  float x1 = fminf(fmaxf(cx - 0.5f * pw, 0.f), 1023.f);
  float y1 = fminf(fmaxf(cy - 0.5f * ph, 0.f), 1023.f);
  float x2 = fminf(fmaxf(cx + 0.5f * pw, 0.f), 1023.f);
  float y2 = fminf(fmaxf(cy + 0.5f * ph, 0.f), 1023.f);

  const long o = ((long)b * 5120 + pos * 5 + a) * 5;
  out[o + 0] = x1;
  out[o + 1] = y1;
  out[o + 2] = x2;
  out[o + 3] = y2;
  out[o + 4] = score;
  out[819200 + (long)b * 5120 + pos * 5 + a] = (float)arg;
}

// ---------------------------------------------------------------------------
// workspace layout (bytes):
//   0          fph  [32][34][34][512] f16   37,879,808
//   37879808   fpl                          37,879,808
//   75759616   A1h  [1024][4608] f16         9,437,184
//   85196800   A1l                           9,437,184
//   94633984   A2h  [512][1024] f16          1,048,576
//   95682560   A2l                           1,048,576
//   96731136   scale f32[1024]                   4,096
//   96735232   shift f32[1024]                   4,096
//   96739328   bias  f32[512]                    2,048
//   96741376   xth  [32768][1024] f16       67,108,864
//   163850240  xtl                          67,108,864
//   total 230,959,104;  preds f32[32768][512] aliases offset 0
// ---------------------------------------------------------------------------
extern "C" void kernel_launch(void* const* d_in, const int* in_sizes, int n_in,
                              void* d_out, int out_size, void* d_ws, size_t ws_size,
                              hipStream_t stream) {
  (void)in_sizes; (void)n_in; (void)out_size; (void)ws_size;
  const float* features = (const float*)d_in[0];
  const float* conv1_w = (const float*)d_in[1];
  const float* bn_g = (const float*)d_in[2];
  const float* bn_b = (const float*)d_in[3];
  const float* bn_m = (const float*)d_in[4];
  const float* bn_v = (const float*)d_in[5];
  const float* conv2_w = (const float*)d_in[6];
  const float* conv2_b = (const float*)d_in[7];
  float* out = (float*)d_out;
  char* ws = (char*)d_ws;

  f16* fph = (f16*)(ws + 0);
  f16* fpl = (f16*)(ws + 37879808L);
  f16* A1h = (f16*)(ws + 75759616L);
  f16* A1l = (f16*)(ws + 85196800L);
  f16* A2h = (f16*)(ws + 94633984L);
  f16* A2l = (f16*)(ws + 95682560L);
  float* scale = (float*)(ws + 96731136L);
  float* shift = (float*)(ws + 96735232L);
  float* bias = (float*)(ws + 96739328L);
  f16* xth = (f16*)(ws + 96741376L);
  f16* xtl = (f16*)(ws + 163850240L);
  float* preds = (float*)(ws + 0);  // alias: fp dead after gemm1

  hipMemsetAsync(ws, 0, 75759616L, stream);  // zero padded feature rings
  prep_misc<<<1, 1024, 0, stream>>>(bn_g, bn_b, bn_m, bn_v, conv2_b, scale, shift, bias);
  prep_w1<<<dim3(1024, 18), 256, 0, stream>>>(conv1_w, A1h, A1l);
  prep_w2<<<dim3(512, 4), 256, 0, stream>>>(conv2_w, A2h, A2l);
  prep_feat<<<dim3(32, 32), 256, 0, stream>>>(features, fph, fpl);
  gemm1<<<dim3(128, 8), 256, 0, stream>>>(A1h, A1l, fph, fpl, scale, shift, xth, xtl);
  gemm2<<<dim3(128, 4), 256, 0, stream>>>(A2h, A2l, xth, xtl, bias, preds);
  decode<<<640, 256, 0, stream>>>(preds, out);
}

// Round 7
// 1124.000 us; speedup vs baseline: 1.1812x; 1.1812x over previous
//
#include <hip/hip_runtime.h>

// ---------------------------------------------------------------------------
// YOLOv2 head on MI355X (gfx950).
// conv1 3x3 (512->1024) + BN + leaky -> conv2 1x1 (1024->425) + bias -> decode
// fp16 3-term split GEMM (ah*bh + ah*bl + al*bh) for fp32-class accuracy.
// R7: R4's proven 256x256 8-wave 4-phase skeleton, upgraded:
//   - 32x32x16 MFMA (fewer instrs, faster pipe; layouts HW-proven in R5/R6)
//   - fragment-order 1KB LDS chunks (32 rows x 16 k, lane-linear, 0 conflicts)
//   - ONE barrier per phase (pre-MFMA) -> waves may skew +-1 phase, so next
//     phase's ds_read/stage overlaps other waves' MFMA clusters
//   - stage spread Ah,Bh@P0 / Al,Bl@P1 / ks1 pairs @P2,P3; vmcnt(4) at P1,P3
// ---------------------------------------------------------------------------

typedef _Float16 f16;
typedef _Float16 f16x8 __attribute__((ext_vector_type(8)));
typedef _Float16 f16x4v __attribute__((ext_vector_type(4)));
typedef float    f32x16 __attribute__((ext_vector_type(16)));

__device__ __forceinline__ void gload16(const f16* g, f16* l) {
  __builtin_amdgcn_global_load_lds(
      (const __attribute__((address_space(1))) void*)g,
      (__attribute__((address_space(3))) void*)l, 16, 0, 0);
}

#define MFMA32(a, b, c) __builtin_amdgcn_mfma_f32_32x32x16_f16(a, b, c, 0, 0, 0)
#define ASM_VMCNT(N) asm volatile("s_waitcnt vmcnt(" #N ")" ::: "memory")
#define SBAR()                           \
  {                                      \
    __builtin_amdgcn_s_barrier();        \
    __builtin_amdgcn_sched_barrier(0);   \
  }

// LDS regions (f16 elems). Each region: 2 bufs x 16 chunks x 512.
// Chunk = 1KB = 32 rows x 16 k, lane-linear: lane l holds row l&31,
// k = (l>>5)*8 + e  (matches 32x32x16 A/B fragment layout, proven R5/R6).
// A chunk index: (row32 * 2 + kstep); B chunk index: (col32 * 2 + kstep).
#define R_AH 0
#define R_AL 16384
#define R_BH 32768
#define R_BL 49152

// anchors
__device__ const float c_AW[5] = {42.f, 98.f, 180.f, 300.f, 400.f};
__device__ const float c_AH_[5] = {45.f, 130.f, 260.f, 180.f, 400.f};

// ---------------------------------------------------------------------------
__global__ void prep_misc(const float* __restrict__ g, const float* __restrict__ be,
                          const float* __restrict__ mn, const float* __restrict__ vr,
                          const float* __restrict__ b2,
                          float* __restrict__ scale, float* __restrict__ shift,
                          float* __restrict__ bias) {
  int i = threadIdx.x;  // 1024 threads
  float s = g[i] / sqrtf(vr[i] + 1e-5f);
  shift[i] = be[i] - mn[i] * s;
  scale[i] = s * (1.0f / 1024.0f);
  if (i < 512) bias[i] = (i < 425) ? b2[i] : 0.f;
}

__global__ __launch_bounds__(256) void prep_w1(const float* __restrict__ w,
                                               f16* __restrict__ Ah, f16* __restrict__ Al) {
  const int co = blockIdx.x;
  const int k = blockIdx.y * 256 + threadIdx.x;  // < 4608
  const int ky = k / 1536, rem = k - ky * 1536;
  const int kx = rem >> 9, ci = rem & 511;
  float v = w[((co * 512 + ci) * 3 + ky) * 3 + kx] * 1024.f;
  f16 h = (f16)v;
  Ah[(long)co * 4608 + k] = h;
  Al[(long)co * 4608 + k] = (f16)(v - (float)h);
}

__global__ __launch_bounds__(256) void prep_w2(const float* __restrict__ w,
                                               f16* __restrict__ Ah, f16* __restrict__ Al) {
  const int co = blockIdx.x;                      // < 512
  const int ci = blockIdx.y * 256 + threadIdx.x;  // < 1024
  float v = (co < 425) ? w[co * 1024 + ci] * 1024.f : 0.f;
  f16 h = (f16)v;
  Ah[co * 1024 + ci] = h;
  Al[co * 1024 + ci] = (f16)(v - (float)h);
}

__global__ __launch_bounds__(256) void prep_feat(const float* __restrict__ f,
                                                 f16* __restrict__ fph, f16* __restrict__ fpl) {
  __shared__ float lds[256][33];
  const int y = blockIdx.x, b = blockIdx.y, t = threadIdx.x;
  const int xx = t & 31, cig = t >> 5;
  const float* src = f + ((long)b * 512) * 1024 + y * 32;

  for (int half = 0; half < 2; ++half) {
    const int cibase = half * 256;
    for (int rep = 0; rep < 32; ++rep) {
      int ci = rep * 8 + cig;
      lds[ci][xx] = src[(long)(cibase + ci) * 1024 + xx];
    }
    __syncthreads();
    const long rowbase = ((long)(b * 34) + (y + 1)) * 34 + 1;
    for (int xp = 0; xp < 32; ++xp) {
      float v = lds[t][xp];
      f16 h = (f16)v;
      long o = (rowbase + xp) * 512 + cibase + t;
      fph[o] = h;
      fpl[o] = (f16)(v - (float)h);
    }
    __syncthreads();
  }
}

// ---------------------------------------------------------------------------
// gemm1: C[1024][32768] = A1(1024x4608) * im2col(features) + BN + leaky.
// 256x256 tile, 8 waves (2Mx4N, per-wave 128x64 = 4x2 cells of 32x32), BK=32
// (2 ksteps), 4 phases/K-tile {ks0 mc01, ks0 mc23, ks1 mc01, ks1 mc23},
// one pre-MFMA barrier per phase, vmcnt(4) at P1/P3. grid (128,4), block 512.
// ---------------------------------------------------------------------------
__global__ __launch_bounds__(512, 2) void gemm1(
    const f16* __restrict__ A1h, const f16* __restrict__ A1l,
    const f16* __restrict__ Bh, const f16* __restrict__ Bl,
    const float* __restrict__ scale, const float* __restrict__ shift,
    f16* __restrict__ xth, f16* __restrict__ xtl) {
  __shared__ __align__(16) f16 S[65536];  // 128 KiB
  const int tid = threadIdx.x;
  const int l = tid & 63, w = tid >> 6;
  const int wm = w >> 2, wn = w & 3;  // per-wave 128(M) x 64(N)
  const int l31 = l & 31, lh = l >> 5;
  const int nt = blockIdx.x, mt = blockIdx.y;
  const int n0 = nt * 256, co0 = mt * 256;
  const int b = n0 >> 10, y0 = (n0 & 1023) >> 5;

  // staging: wave w owns A row32=w and B col32=w, both ksteps, hi&lo.
  const long aS = (long)(co0 + w * 32 + l31) * 4608 + lh * 8;
  const long bS = ((long)(b * 34 + y0 + w) * 34 + l31) * 512 + lh * 8;
  const int dW = w * 2 * 512;  // LDS dest chunk base (chunk (w,ks) = dW+ks*512)
  const int lro = l * 8;

  f32x16 acc[4][2] = {};  // [mc][nc]
  f16x8 ah[2], al[2], bh[2], bl[2];

  // prologue: stage tile 0 (ks0 quad first, then ks1 quad)
  gload16(A1h + aS, &S[R_AH + dW]);
  gload16(Bh + bS, &S[R_BH + dW]);
  gload16(A1l + aS, &S[R_AL + dW]);
  gload16(Bl + bS, &S[R_BL + dW]);
  gload16(A1h + aS + 16, &S[R_AH + dW + 512]);
  gload16(Bh + bS + 16, &S[R_BH + dW + 512]);
  gload16(A1l + aS + 16, &S[R_AL + dW + 512]);
  gload16(Bl + bS + 16, &S[R_BL + dW + 512]);
  ASM_VMCNT(4);  // ks0 quad complete (ks1 guaranteed at first P1 vmcnt)
  SBAR();

  for (int t = 0; t < 144; ++t) {
    const int cb = (t & 1) << 13;  // current buf (f16 elems)
    const int nb = 8192 - cb;      // next buf
    const int s1 = (t < 143) ? t + 1 : t;  // clamped prefetch tile
    const int ky1 = s1 / 48, r1 = s1 - ky1 * 48;
    const int kx1 = r1 >> 4, ci1 = (r1 & 15) << 5;
    const long kA = (long)s1 * 32;
    const long kB = (long)(ky1 * 34 + kx1) * 512 + ci1;

    // ---- P0: ks0, mc{0,1} ----
    gload16(A1h + aS + kA, &S[R_AH + nb + dW]);
    gload16(Bh + bS + kB, &S[R_BH + nb + dW]);
#pragma unroll
    for (int mc = 0; mc < 2; ++mc) {
      const int ca = ((wm * 4 + mc) * 2) * 512;
      ah[mc] = *(const f16x8*)&S[R_AH + cb + ca + lro];
      al[mc] = *(const f16x8*)&S[R_AL + cb + ca + lro];
    }
#pragma unroll
    for (int nc = 0; nc < 2; ++nc) {
      const int cbk = ((wn * 2 + nc) * 2) * 512;
      bh[nc] = *(const f16x8*)&S[R_BH + cb + cbk + lro];
      bl[nc] = *(const f16x8*)&S[R_BL + cb + cbk + lro];
    }
    SBAR();
    __builtin_amdgcn_s_setprio(1);
#pragma unroll
    for (int mc = 0; mc < 2; ++mc)
#pragma unroll
      for (int nc = 0; nc < 2; ++nc) {
        acc[mc][nc] = MFMA32(ah[mc], bh[nc], acc[mc][nc]);
        acc[mc][nc] = MFMA32(ah[mc], bl[nc], acc[mc][nc]);
        acc[mc][nc] = MFMA32(al[mc], bh[nc], acc[mc][nc]);
      }
    __builtin_amdgcn_s_setprio(0);

    // ---- P1: ks0, mc{2,3} (reuse bh/bl) ----
    gload16(A1l + aS + kA, &S[R_AL + nb + dW]);
    gload16(Bl + bS + kB, &S[R_BL + nb + dW]);
#pragma unroll
    for (int mc = 0; mc < 2; ++mc) {
      const int ca = ((wm * 4 + 2 + mc) * 2) * 512;
      ah[mc] = *(const f16x8*)&S[R_AH + cb + ca + lro];
      al[mc] = *(const f16x8*)&S[R_AL + cb + ca + lro];
    }
    ASM_VMCNT(4);  // drains prev-iter P2/P3 stages (this tile's ks1 chunks)
    SBAR();
    __builtin_amdgcn_s_setprio(1);
#pragma unroll
    for (int mc = 0; mc < 2; ++mc)
#pragma unroll
      for (int nc = 0; nc < 2; ++nc) {
        acc[2 + mc][nc] = MFMA32(ah[mc], bh[nc], acc[2 + mc][nc]);
        acc[2 + mc][nc] = MFMA32(ah[mc], bl[nc], acc[2 + mc][nc]);
        acc[2 + mc][nc] = MFMA32(al[mc], bh[nc], acc[2 + mc][nc]);
      }
    __builtin_amdgcn_s_setprio(0);

    // ---- P2: ks1, mc{0,1} ----
    gload16(A1h + aS + kA + 16, &S[R_AH + nb + dW + 512]);
    gload16(Bh + bS + kB + 16, &S[R_BH + nb + dW + 512]);
#pragma unroll
    for (int mc = 0; mc < 2; ++mc) {
      const int ca = ((wm * 4 + mc) * 2 + 1) * 512;
      ah[mc] = *(const f16x8*)&S[R_AH + cb + ca + lro];
      al[mc] = *(const f16x8*)&S[R_AL + cb + ca + lro];
    }
#pragma unroll
    for (int nc = 0; nc < 2; ++nc) {
      const int cbk = ((wn * 2 + nc) * 2 + 1) * 512;
      bh[nc] = *(const f16x8*)&S[R_BH + cb + cbk + lro];
      bl[nc] = *(const f16x8*)&S[R_BL + cb + cbk + lro];
    }
    SBAR();
    __builtin_amdgcn_s_setprio(1);
#pragma unroll
    for (int mc = 0; mc < 2; ++mc)
#pragma unroll
      for (int nc = 0; nc < 2; ++nc) {
        acc[mc][nc] = MFMA32(ah[mc], bh[nc], acc[mc][nc]);
        acc[mc][nc] = MFMA32(ah[mc], bl[nc], acc[mc][nc]);
        acc[mc][nc] = MFMA32(al[mc], bh[nc], acc[mc][nc]);
      }
    __builtin_amdgcn_s_setprio(0);

    // ---- P3: ks1, mc{2,3} (reuse bh/bl) ----
    gload16(A1l + aS + kA + 16, &S[R_AL + nb + dW + 512]);
    gload16(Bl + bS + kB + 16, &S[R_BL + nb + dW + 512]);
#pragma unroll
    for (int mc = 0; mc < 2; ++mc) {
      const int ca = ((wm * 4 + 2 + mc) * 2 + 1) * 512;
      ah[mc] = *(const f16x8*)&S[R_AH + cb + ca + lro];
      al[mc] = *(const f16x8*)&S[R_AL + cb + ca + lro];
    }
    ASM_VMCNT(4);  // drains this-iter P0/P1 stages (next tile's ks0 chunks)
    SBAR();
    __builtin_amdgcn_s_setprio(1);
#pragma unroll
    for (int mc = 0; mc < 2; ++mc)
#pragma unroll
      for (int nc = 0; nc < 2; ++nc) {
        acc[2 + mc][nc] = MFMA32(ah[mc], bh[nc], acc[2 + mc][nc]);
        acc[2 + mc][nc] = MFMA32(ah[mc], bl[nc], acc[2 + mc][nc]);
        acc[2 + mc][nc] = MFMA32(al[mc], bh[nc], acc[2 + mc][nc]);
      }
    __builtin_amdgcn_s_setprio(0);
  }

  // epilogue: BN (1/1024 folded) + leaky, split to fp16 hi/lo, store NHWC.
  // 32x32 C/D: col = lane&31, row = (reg&3) + 8*(reg>>2) + 4*(lane>>5)
#pragma unroll
  for (int mc = 0; mc < 4; ++mc) {
#pragma unroll
    for (int nc = 0; nc < 2; ++nc) {
      const int colB = n0 + wn * 64 + nc * 32 + l31;
      const long colOff = (long)colB * 1024;
#pragma unroll
      for (int rg = 0; rg < 4; ++rg) {
        const int cob = co0 + wm * 128 + mc * 32 + rg * 8 + lh * 4;
        const float4 scv = *(const float4*)(scale + cob);
        const float4 shv = *(const float4*)(shift + cob);
        float v0 = acc[mc][nc][rg * 4 + 0] * scv.x + shv.x; v0 = v0 > 0.f ? v0 : 0.1f * v0;
        float v1 = acc[mc][nc][rg * 4 + 1] * scv.y + shv.y; v1 = v1 > 0.f ? v1 : 0.1f * v1;
        float v2 = acc[mc][nc][rg * 4 + 2] * scv.z + shv.z; v2 = v2 > 0.f ? v2 : 0.1f * v2;
        float v3 = acc[mc][nc][rg * 4 + 3] * scv.w + shv.w; v3 = v3 > 0.f ? v3 : 0.1f * v3;
        f16 h0 = (f16)v0, h1 = (f16)v1, h2 = (f16)v2, h3 = (f16)v3;
        f16x4v hv = {h0, h1, h2, h3};
        f16x4v lv = {(f16)(v0 - (float)h0), (f16)(v1 - (float)h1),
                     (f16)(v2 - (float)h2), (f16)(v3 - (float)h3)};
        *(f16x4v*)(xth + colOff + cob) = hv;
        *(f16x4v*)(xtl + colOff + cob) = lv;
      }
    }
  }
}

// ---------------------------------------------------------------------------
// gemm2: preds[n][512] = A2(512x1024) * xt (+bias, /1024). Same structure.
// grid (128, 2), block 512, 32 K-tiles.
// ---------------------------------------------------------------------------
__global__ __launch_bounds__(512, 2) void gemm2(
    const f16* __restrict__ A2h, const f16* __restrict__ A2l,
    const f16* __restrict__ Bh, const f16* __restrict__ Bl,
    const float* __restrict__ bias, float* __restrict__ preds) {
  __shared__ __align__(16) f16 S[65536];
  const int tid = threadIdx.x;
  const int l = tid & 63, w = tid >> 6;
  const int wm = w >> 2, wn = w & 3;
  const int l31 = l & 31, lh = l >> 5;
  const int nt = blockIdx.x, mt = blockIdx.y;
  const int n0 = nt * 256, co0 = mt * 256;

  const long aS = (long)(co0 + w * 32 + l31) * 1024 + lh * 8;
  const long bS = (long)(n0 + w * 32 + l31) * 1024 + lh * 8;
  const int dW = w * 2 * 512;
  const int lro = l * 8;

  f32x16 acc[4][2] = {};
  f16x8 ah[2], al[2], bh[2], bl[2];

  gload16(A2h + aS, &S[R_AH + dW]);
  gload16(Bh + bS, &S[R_BH + dW]);
  gload16(A2l + aS, &S[R_AL + dW]);
  gload16(Bl + bS, &S[R_BL + dW]);
  gload16(A2h + aS + 16, &S[R_AH + dW + 512]);
  gload16(Bh + bS + 16, &S[R_BH + dW + 512]);
  gload16(A2l + aS + 16, &S[R_AL + dW + 512]);
  gload16(Bl + bS + 16, &S[R_BL + dW + 512]);
  ASM_VMCNT(4);
  SBAR();

  for (int t = 0; t < 32; ++t) {
    const int cb = (t & 1) << 13;
    const int nb = 8192 - cb;
    const long kA = (long)((t < 31) ? t + 1 : t) * 32;

    // ---- P0 ----
    gload16(A2h + aS + kA, &S[R_AH + nb + dW]);
    gload16(Bh + bS + kA, &S[R_BH + nb + dW]);
#pragma unroll
    for (int mc = 0; mc < 2; ++mc) {
      const int ca = ((wm * 4 + mc) * 2) * 512;
      ah[mc] = *(const f16x8*)&S[R_AH + cb + ca + lro];
      al[mc] = *(const f16x8*)&S[R_AL + cb + ca + lro];
    }
#pragma unroll
    for (int nc = 0; nc < 2; ++nc) {
      const int cbk = ((wn * 2 + nc) * 2) * 512;
      bh[nc] = *(const f16x8*)&S[R_BH + cb + cbk + lro];
      bl[nc] = *(const f16x8*)&S[R_BL + cb + cbk + lro];
    }
    SBAR();
    __builtin_amdgcn_s_setprio(1);
#pragma unroll
    for (int mc = 0; mc < 2; ++mc)
#pragma unroll
      for (int nc = 0; nc < 2; ++nc) {
        acc[mc][nc] = MFMA32(ah[mc], bh[nc], acc[mc][nc]);
        acc[mc][nc] = MFMA32(ah[mc], bl[nc], acc[mc][nc]);
        acc[mc][nc] = MFMA32(al[mc], bh[nc], acc[mc][nc]);
      }
    __builtin_amdgcn_s_setprio(0);

    // ---- P1 ----
    gload16(A2l + aS + kA, &S[R_AL + nb + dW]);
    gload16(Bl + bS + kA, &S[R_BL + nb + dW]);
#pragma unroll
    for (int mc = 0; mc < 2; ++mc) {
      const int ca = ((wm * 4 + 2 + mc) * 2) * 512;
      ah[mc] = *(const f16x8*)&S[R_AH + cb + ca + lro];
      al[mc] = *(const f16x8*)&S[R_AL + cb + ca + lro];
    }
    ASM_VMCNT(4);
    SBAR();
    __builtin_amdgcn_s_setprio(1);
#pragma unroll
    for (int mc = 0; mc < 2; ++mc)
#pragma unroll
      for (int nc = 0; nc < 2; ++nc) {
        acc[2 + mc][nc] = MFMA32(ah[mc], bh[nc], acc[2 + mc][nc]);
        acc[2 + mc][nc] = MFMA32(ah[mc], bl[nc], acc[2 + mc][nc]);
        acc[2 + mc][nc] = MFMA32(al[mc], bh[nc], acc[2 + mc][nc]);
      }
    __builtin_amdgcn_s_setprio(0);

    // ---- P2 ----
    gload16(A2h + aS + kA + 16, &S[R_AH + nb + dW + 512]);
    gload16(Bh + bS + kA + 16, &S[R_BH + nb + dW + 512]);
#pragma unroll
    for (int mc = 0; mc < 2; ++mc) {
      const int ca = ((wm * 4 + mc) * 2 + 1) * 512;
      ah[mc] = *(const f16x8*)&S[R_AH + cb + ca + lro];
      al[mc] = *(const f16x8*)&S[R_AL + cb + ca + lro];
    }
#pragma unroll
    for (int nc = 0; nc < 2; ++nc) {
      const int cbk = ((wn * 2 + nc) * 2 + 1) * 512;
      bh[nc] = *(const f16x8*)&S[R_BH + cb + cbk + lro];
      bl[nc] = *(const f16x8*)&S[R_BL + cb + cbk + lro];
    }
    SBAR();
    __builtin_amdgcn_s_setprio(1);
#pragma unroll
    for (int mc = 0; mc < 2; ++mc)
#pragma unroll
      for (int nc = 0; nc < 2; ++nc) {
        acc[mc][nc] = MFMA32(ah[mc], bh[nc], acc[mc][nc]);
        acc[mc][nc] = MFMA32(ah[mc], bl[nc], acc[mc][nc]);
        acc[mc][nc] = MFMA32(al[mc], bh[nc], acc[mc][nc]);
      }
    __builtin_amdgcn_s_setprio(0);

    // ---- P3 ----
    gload16(A2l + aS + kA + 16, &S[R_AL + nb + dW + 512]);
    gload16(Bl + bS + kA + 16, &S[R_BL + nb + dW + 512]);
#pragma unroll
    for (int mc = 0; mc < 2; ++mc) {
      const int ca = ((wm * 4 + 2 + mc) * 2 + 1) * 512;
      ah[mc] = *(const f16x8*)&S[R_AH + cb + ca + lro];
      al[mc] = *(const f16x8*)&S[R_AL + cb + ca + lro];
    }
    ASM_VMCNT(4);
    SBAR();
    __builtin_amdgcn_s_setprio(1);
#pragma unroll
    for (int mc = 0; mc < 2; ++mc)
#pragma unroll
      for (int nc = 0; nc < 2; ++nc) {
        acc[2 + mc][nc] = MFMA32(ah[mc], bh[nc], acc[2 + mc][nc]);
        acc[2 + mc][nc] = MFMA32(ah[mc], bl[nc], acc[2 + mc][nc]);
        acc[2 + mc][nc] = MFMA32(al[mc], bh[nc], acc[2 + mc][nc]);
      }
    __builtin_amdgcn_s_setprio(0);
  }

#pragma unroll
  for (int mc = 0; mc < 4; ++mc) {
#pragma unroll
    for (int nc = 0; nc < 2; ++nc) {
      const int colB = n0 + wn * 64 + nc * 32 + l31;
      const long colOff = (long)colB * 512;
#pragma unroll
      for (int rg = 0; rg < 4; ++rg) {
        const int cob = co0 + wm * 128 + mc * 32 + rg * 8 + lh * 4;
        const float4 bi = *(const float4*)(bias + cob);
        float4 o;
        o.x = acc[mc][nc][rg * 4 + 0] * 9.765625e-4f + bi.x;
        o.y = acc[mc][nc][rg * 4 + 1] * 9.765625e-4f + bi.y;
        o.z = acc[mc][nc][rg * 4 + 2] * 9.765625e-4f + bi.z;
        o.w = acc[mc][nc][rg * 4 + 3] * 9.765625e-4f + bi.w;
        *(float4*)(preds + colOff + cob) = o;
      }
    }
  }
}

// ---------------------------------------------------------------------------
__global__ __launch_bounds__(256) void decode(const float* __restrict__ preds,
                                              float* __restrict__ out) {
  const int t = blockIdx.x * 256 + threadIdx.x;  // < 163840
  const int b = t / 5120, rem = t % 5120, pos = rem / 5, a = rem % 5;
  const int n = (b << 10) + pos;
  const float* p = preds + (long)n * 512 + a * 85;

  float tx = p[0], ty = p[1], tw = p[2], th = p[3], to = p[4];
  float mx = p[5];
  int arg = 0;
  for (int i = 1; i < 80; ++i) {
    float v = p[5 + i];
    if (v > mx) { mx = v; arg = i; }
  }
  float sum = 0.f;
  for (int i = 0; i < 80; ++i) sum += expf(p[5 + i] - mx);

  float obj = 1.f / (1.f + expf(-to));
  float score = obj / sum;
  float bx = 1.f / (1.f + expf(-tx));
  float by = 1.f / (1.f + expf(-ty));
  float bw = expf(fminf(tw, 8.f));
  float bh2 = expf(fminf(th, 8.f));
  float cx = (bx + (float)(pos & 31)) * 32.f;
  float cy = (by + (float)(pos >> 5)) * 32.f;
  float pw = c_AW[a] * bw;
  float ph = c_AH_[a] * bh2;
  float x1 = fminf(fmaxf(cx - 0.5f * pw, 0.f), 1023.f);
  float y1 = fminf(fmaxf(cy - 0.5f * ph, 0.f), 1023.f);
  float x2 = fminf(fmaxf(cx + 0.5f * pw, 0.f), 1023.f);
  float y2 = fminf(fmaxf(cy + 0.5f * ph, 0.f), 1023.f);

  const long o = ((long)b * 5120 + pos * 5 + a) * 5;
  out[o + 0] = x1;
  out[o + 1] = y1;
  out[o + 2] = x2;
  out[o + 3] = y2;
  out[o + 4] = score;
  out[819200 + (long)b * 5120 + pos * 5 + a] = (float)arg;
}

// ---------------------------------------------------------------------------
// workspace layout (bytes):
//   0          fph  [32][34][34][512] f16   37,879,808
//   37879808   fpl                          37,879,808
//   75759616   A1h  [1024][4608] f16         9,437,184
//   85196800   A1l                           9,437,184
//   94633984   A2h  [512][1024] f16          1,048,576
//   95682560   A2l                           1,048,576
//   96731136   scale f32[1024]                   4,096
//   96735232   shift f32[1024]                   4,096
//   96739328   bias  f32[512]                    2,048
//   96741376   xth  [32768][1024] f16       67,108,864
//   163850240  xtl                          67,108,864
//   total 230,959,104;  preds f32[32768][512] aliases offset 0
// ---------------------------------------------------------------------------
extern "C" void kernel_launch(void* const* d_in, const int* in_sizes, int n_in,
                              void* d_out, int out_size, void* d_ws, size_t ws_size,
                              hipStream_t stream) {
  (void)in_sizes; (void)n_in; (void)out_size; (void)ws_size;
  const float* features = (const float*)d_in[0];
  const float* conv1_w = (const float*)d_in[1];
  const float* bn_g = (const float*)d_in[2];
  const float* bn_b = (const float*)d_in[3];
  const float* bn_m = (const float*)d_in[4];
  const float* bn_v = (const float*)d_in[5];
  const float* conv2_w = (const float*)d_in[6];
  const float* conv2_b = (const float*)d_in[7];
  float* out = (float*)d_out;
  char* ws = (char*)d_ws;

  f16* fph = (f16*)(ws + 0);
  f16* fpl = (f16*)(ws + 37879808L);
  f16* A1h = (f16*)(ws + 75759616L);
  f16* A1l = (f16*)(ws + 85196800L);
  f16* A2h = (f16*)(ws + 94633984L);
  f16* A2l = (f16*)(ws + 95682560L);
  float* scale = (float*)(ws + 96731136L);
  float* shift = (float*)(ws + 96735232L);
  float* bias = (float*)(ws + 96739328L);
  f16* xth = (f16*)(ws + 96741376L);
  f16* xtl = (f16*)(ws + 163850240L);
  float* preds = (float*)(ws + 0);  // alias: fp dead after gemm1

  hipMemsetAsync(ws, 0, 75759616L, stream);  // zero padded feature rings
  prep_misc<<<1, 1024, 0, stream>>>(bn_g, bn_b, bn_m, bn_v, conv2_b, scale, shift, bias);
  prep_w1<<<dim3(1024, 18), 256, 0, stream>>>(conv1_w, A1h, A1l);
  prep_w2<<<dim3(512, 4), 256, 0, stream>>>(conv2_w, A2h, A2l);
  prep_feat<<<dim3(32, 32), 256, 0, stream>>>(features, fph, fpl);
  gemm1<<<dim3(128, 4), 512, 0, stream>>>(A1h, A1l, fph, fpl, scale, shift, xth, xtl);
  gemm2<<<dim3(128, 2), 512, 0, stream>>>(A2h, A2l, xth, xtl, bias, preds);
  decode<<<640, 256, 0, stream>>>(preds, out);
}

// Round 8
// 883.747 us; speedup vs baseline: 1.5023x; 1.2719x over previous
//
#include <hip/hip_runtime.h>

// ---------------------------------------------------------------------------
// YOLOv2 head on MI355X (gfx950).
// conv1 3x3 (512->1024) + BN + leaky -> conv2 1x1 (1024->425) + bias -> decode
// fp16 3-term split GEMM (ah*bh + ah*bl + al*bh) for fp32-class accuracy.
// R8 = R4 (proven 795us) + two surgical edits:
//   (1) trailing per-phase barrier removed (4 barriers/K-tile, pre-MFMA only)
//       - P0(t) reads protected by BAR@P3(t-1) (all waves' vmcnt(4) precede it)
//       - P1/P2(t) reads protected by vmcnt(2)+BAR@P0(t)
//       - WAR: stages are >=2 pre-MFMA barriers after last readers' lgkm waits
//   (2) B-fragment register caching: P2 reuses P0's B frags, P3 reuses P1's
//       (ds_reads 32 -> 24 per wave per K-tile). 16x16x32 MFMA kept (32x32
//       regressed in R5/R7).
// ---------------------------------------------------------------------------

typedef _Float16 f16;
typedef _Float16 f16x8 __attribute__((ext_vector_type(8)));
typedef _Float16 f16x4v __attribute__((ext_vector_type(4)));
typedef float    f32x4 __attribute__((ext_vector_type(4)));

__device__ __forceinline__ void gload16(const f16* g, f16* l) {
  __builtin_amdgcn_global_load_lds(
      (const __attribute__((address_space(1))) void*)g,
      (__attribute__((address_space(3))) void*)l, 16, 0, 0);
}

#define MFMA(a, b, c) __builtin_amdgcn_mfma_f32_16x16x32_f16(a, b, c, 0, 0, 0)
#define ASM_VMCNT(N) asm volatile("s_waitcnt vmcnt(" #N ")" ::: "memory")
#define SBAR()                           \
  {                                      \
    __builtin_amdgcn_s_barrier();        \
    __builtin_amdgcn_sched_barrier(0);   \
  }

// LDS region bases (f16 elements): each region 2 bufs x 16 units x 512
#define R_AH 0
#define R_AL 16384
#define R_BH 32768
#define R_BL 49152

// anchors
__device__ const float c_AW[5] = {42.f, 98.f, 180.f, 300.f, 400.f};
__device__ const float c_AH_[5] = {45.f, 130.f, 260.f, 180.f, 400.f};

// ---------------------------------------------------------------------------
__global__ void prep_misc(const float* __restrict__ g, const float* __restrict__ be,
                          const float* __restrict__ mn, const float* __restrict__ vr,
                          const float* __restrict__ b2,
                          float* __restrict__ scale, float* __restrict__ shift,
                          float* __restrict__ bias) {
  int i = threadIdx.x;  // 1024 threads
  float s = g[i] / sqrtf(vr[i] + 1e-5f);
  shift[i] = be[i] - mn[i] * s;
  scale[i] = s * (1.0f / 1024.0f);
  if (i < 512) bias[i] = (i < 425) ? b2[i] : 0.f;
}

__global__ __launch_bounds__(256) void prep_w1(const float* __restrict__ w,
                                               f16* __restrict__ Ah, f16* __restrict__ Al) {
  const int co = blockIdx.x;
  const int k = blockIdx.y * 256 + threadIdx.x;  // < 4608
  const int ky = k / 1536, rem = k - ky * 1536;
  const int kx = rem >> 9, ci = rem & 511;
  float v = w[((co * 512 + ci) * 3 + ky) * 3 + kx] * 1024.f;
  f16 h = (f16)v;
  Ah[(long)co * 4608 + k] = h;
  Al[(long)co * 4608 + k] = (f16)(v - (float)h);
}

__global__ __launch_bounds__(256) void prep_w2(const float* __restrict__ w,
                                               f16* __restrict__ Ah, f16* __restrict__ Al) {
  const int co = blockIdx.x;                      // < 512
  const int ci = blockIdx.y * 256 + threadIdx.x;  // < 1024
  float v = (co < 425) ? w[co * 1024 + ci] * 1024.f : 0.f;
  f16 h = (f16)v;
  Ah[co * 1024 + ci] = h;
  Al[co * 1024 + ci] = (f16)(v - (float)h);
}

__global__ __launch_bounds__(256) void prep_feat(const float* __restrict__ f,
                                                 f16* __restrict__ fph, f16* __restrict__ fpl) {
  __shared__ float lds[256][33];
  const int y = blockIdx.x, b = blockIdx.y, t = threadIdx.x;
  const int xx = t & 31, cig = t >> 5;
  const float* src = f + ((long)b * 512) * 1024 + y * 32;

  for (int half = 0; half < 2; ++half) {
    const int cibase = half * 256;
    for (int rep = 0; rep < 32; ++rep) {
      int ci = rep * 8 + cig;
      lds[ci][xx] = src[(long)(cibase + ci) * 1024 + xx];
    }
    __syncthreads();
    const long rowbase = ((long)(b * 34) + (y + 1)) * 34 + 1;
    for (int xp = 0; xp < 32; ++xp) {
      float v = lds[t][xp];
      f16 h = (f16)v;
      long o = (rowbase + xp) * 512 + cibase + t;
      fph[o] = h;
      fpl[o] = (f16)(v - (float)h);
    }
    __syncthreads();
  }
}

// ---------------------------------------------------------------------------
// gemm1: C[1024][32768] = A1(1024x4608) * im2col(features) + BN + leaky.
// 256x256 tile, 8 waves (2Mx4N), BK=32, 4 phases/K-tile, double-buffered LDS.
// grid (128 n-tiles, 4 m-tiles), block 512.
// ---------------------------------------------------------------------------
__global__ __launch_bounds__(512, 2) void gemm1(
    const f16* __restrict__ A1h, const f16* __restrict__ A1l,
    const f16* __restrict__ Bh, const f16* __restrict__ Bl,
    const float* __restrict__ scale, const float* __restrict__ shift,
    f16* __restrict__ xth, f16* __restrict__ xtl) {
  __shared__ __align__(16) f16 S[65536];  // 128 KiB
  const int tid = threadIdx.x;
  const int l = tid & 63, w = tid >> 6;
  const int wm = w >> 2, wn = w & 3;
  const int rho = l & 15, cq = l >> 4;
  const int sc = (cq - rho) & 3;                       // stage source chunk
  const int roff = (rho + 16 * ((cq + rho) & 3)) * 8;  // swizzled read slot
  const int nt = blockIdx.x, mt = blockIdx.y;
  const int n0 = nt * 256, co0 = mt * 256;
  const int b = n0 >> 10, y0 = (n0 & 1023) >> 5;

  // stage units per wave
  const int a0u = (w & 3) + (w >> 2) * 8;  // A-half0 rows: units {0..3, 8..11}
  const int a1u = a0u + 4;                 // A-half1
  const int b0u = (w & 1) + (w >> 1) * 4;  // B-half0 cols
  const int b1u = b0u + 2;                 // B-half1

  const long aS0 = (long)(co0 + a0u * 16 + rho) * 4608 + sc * 8;
  const long aS1 = (long)(co0 + a1u * 16 + rho) * 4608 + sc * 8;
  const int c0 = b0u * 16 + rho, c1 = b1u * 16 + rho;
  const long bS0 = ((long)(b * 34 + y0 + (c0 >> 5)) * 34 + (c0 & 31)) * 512 + sc * 8;
  const long bS1 = ((long)(b * 34 + y0 + (c1 >> 5)) * 34 + (c1 & 31)) * 512 + sc * 8;

  f32x4 acc[8][4] = {};
  f16x8 ah[4], al[4], bh0[2], bl0[2], bh1[2], bl1[2];

  // prologue: stage tile 0 (order: a0u hi/lo, b0u hi/lo, a1u hi/lo, b1u hi/lo)
  gload16(A1h + aS0, &S[R_AH + a0u * 512]);
  gload16(A1l + aS0, &S[R_AL + a0u * 512]);
  gload16(Bh + bS0, &S[R_BH + b0u * 512]);
  gload16(Bl + bS0, &S[R_BL + b0u * 512]);
  gload16(A1h + aS1, &S[R_AH + a1u * 512]);
  gload16(A1l + aS1, &S[R_AL + a1u * 512]);
  gload16(Bh + bS1, &S[R_BH + b1u * 512]);
  gload16(Bl + bS1, &S[R_BL + b1u * 512]);
  ASM_VMCNT(4);  // first 4 (a0u,b0u) landed across all waves after barrier
  SBAR();

  for (int t = 0; t < 144; ++t) {
    const int cb = (t & 1) << 13;  // current buf (f16 elems)
    const int nb = 8192 - cb;      // next buf
    const int s1 = (t < 143) ? t + 1 : t;  // clamped prefetch tile
    const int ky1 = s1 / 48, r1 = s1 - ky1 * 48;
    const int kx1 = r1 >> 4, ci1 = (r1 & 15) << 5;
    const long kAn = (long)s1 * 32;
    const long kBn = (long)(ky1 * 34 + kx1) * 512 + ci1;

    // ---- P0: mq=0, nq=0 ---- (reads protected by BAR@P3(t-1))
#pragma unroll
    for (int mf = 0; mf < 4; ++mf) {
      const int u = wm * 8 + mf;
      ah[mf] = *(const f16x8*)&S[R_AH + cb + u * 512 + roff];
      al[mf] = *(const f16x8*)&S[R_AL + cb + u * 512 + roff];
    }
#pragma unroll
    for (int nf = 0; nf < 2; ++nf) {
      const int u = wn * 4 + nf;
      bh0[nf] = *(const f16x8*)&S[R_BH + cb + u * 512 + roff];
      bl0[nf] = *(const f16x8*)&S[R_BL + cb + u * 512 + roff];
    }
    gload16(A1h + aS0 + kAn, &S[R_AH + nb + a0u * 512]);
    gload16(A1l + aS0 + kAn, &S[R_AL + nb + a0u * 512]);
    ASM_VMCNT(2);  // drains P2(t-1)+P3(t-1) stages; leaves own 2
    SBAR();
    __builtin_amdgcn_s_setprio(1);
#pragma unroll
    for (int mf = 0; mf < 4; ++mf)
#pragma unroll
      for (int nf = 0; nf < 2; ++nf) {
        acc[mf][nf] = MFMA(ah[mf], bh0[nf], acc[mf][nf]);
        acc[mf][nf] = MFMA(ah[mf], bl0[nf], acc[mf][nf]);
        acc[mf][nf] = MFMA(al[mf], bh0[nf], acc[mf][nf]);
      }
    __builtin_amdgcn_s_setprio(0);

    // ---- P1: mq=0, nq=1 ---- (reuse ah/al; read B-nq1)
#pragma unroll
    for (int nf = 0; nf < 2; ++nf) {
      const int u = wn * 4 + 2 + nf;
      bh1[nf] = *(const f16x8*)&S[R_BH + cb + u * 512 + roff];
      bl1[nf] = *(const f16x8*)&S[R_BL + cb + u * 512 + roff];
    }
    gload16(Bh + bS0 + kBn, &S[R_BH + nb + b0u * 512]);
    gload16(Bl + bS0 + kBn, &S[R_BL + nb + b0u * 512]);
    SBAR();
    __builtin_amdgcn_s_setprio(1);
#pragma unroll
    for (int mf = 0; mf < 4; ++mf)
#pragma unroll
      for (int nf = 0; nf < 2; ++nf) {
        acc[mf][2 + nf] = MFMA(ah[mf], bh1[nf], acc[mf][2 + nf]);
        acc[mf][2 + nf] = MFMA(ah[mf], bl1[nf], acc[mf][2 + nf]);
        acc[mf][2 + nf] = MFMA(al[mf], bh1[nf], acc[mf][2 + nf]);
      }
    __builtin_amdgcn_s_setprio(0);

    // ---- P2: mq=1, nq=0 ---- (read A-mq1; reuse bh0/bl0 from registers)
#pragma unroll
    for (int mf = 0; mf < 4; ++mf) {
      const int u = wm * 8 + 4 + mf;
      ah[mf] = *(const f16x8*)&S[R_AH + cb + u * 512 + roff];
      al[mf] = *(const f16x8*)&S[R_AL + cb + u * 512 + roff];
    }
    gload16(A1h + aS1 + kAn, &S[R_AH + nb + a1u * 512]);
    gload16(A1l + aS1 + kAn, &S[R_AL + nb + a1u * 512]);
    SBAR();
    __builtin_amdgcn_s_setprio(1);
#pragma unroll
    for (int mf = 0; mf < 4; ++mf)
#pragma unroll
      for (int nf = 0; nf < 2; ++nf) {
        acc[4 + mf][nf] = MFMA(ah[mf], bh0[nf], acc[4 + mf][nf]);
        acc[4 + mf][nf] = MFMA(ah[mf], bl0[nf], acc[4 + mf][nf]);
        acc[4 + mf][nf] = MFMA(al[mf], bh0[nf], acc[4 + mf][nf]);
      }
    __builtin_amdgcn_s_setprio(0);

    // ---- P3: mq=1, nq=1 ---- (no ds_reads: reuse ah/al + bh1/bl1)
    gload16(Bh + bS1 + kBn, &S[R_BH + nb + b1u * 512]);
    gload16(Bl + bS1 + kBn, &S[R_BL + nb + b1u * 512]);
    ASM_VMCNT(4);  // drains P0(t),P1(t) stages (next tile's a0u,b0u)
    SBAR();
    __builtin_amdgcn_s_setprio(1);
#pragma unroll
    for (int mf = 0; mf < 4; ++mf)
#pragma unroll
      for (int nf = 0; nf < 2; ++nf) {
        acc[4 + mf][2 + nf] = MFMA(ah[mf], bh1[nf], acc[4 + mf][2 + nf]);
        acc[4 + mf][2 + nf] = MFMA(ah[mf], bl1[nf], acc[4 + mf][2 + nf]);
        acc[4 + mf][2 + nf] = MFMA(al[mf], bh1[nf], acc[4 + mf][2 + nf]);
      }
    __builtin_amdgcn_s_setprio(0);
  }

  // epilogue: BN (1/1024 folded) + leaky, split to fp16 hi/lo, store NHWC
#pragma unroll
  for (int am = 0; am < 8; ++am) {
    const int cob = co0 + wm * 128 + am * 16 + cq * 4;
    const float4 scv = *(const float4*)(scale + cob);
    const float4 shv = *(const float4*)(shift + cob);
#pragma unroll
    for (int an = 0; an < 4; ++an) {
      const int col = n0 + wn * 64 + an * 16 + rho;
      f32x4 a = acc[am][an];
      float v0 = a[0] * scv.x + shv.x; v0 = v0 > 0.f ? v0 : 0.1f * v0;
      float v1 = a[1] * scv.y + shv.y; v1 = v1 > 0.f ? v1 : 0.1f * v1;
      float v2 = a[2] * scv.z + shv.z; v2 = v2 > 0.f ? v2 : 0.1f * v2;
      float v3 = a[3] * scv.w + shv.w; v3 = v3 > 0.f ? v3 : 0.1f * v3;
      f16 h0 = (f16)v0, h1 = (f16)v1, h2 = (f16)v2, h3 = (f16)v3;
      f16x4v hv = {h0, h1, h2, h3};
      f16x4v lv = {(f16)(v0 - (float)h0), (f16)(v1 - (float)h1),
                   (f16)(v2 - (float)h2), (f16)(v3 - (float)h3)};
      *(f16x4v*)(xth + (long)col * 1024 + cob) = hv;
      *(f16x4v*)(xtl + (long)col * 1024 + cob) = lv;
    }
  }
}

// ---------------------------------------------------------------------------
// gemm2: preds[n][512] = A2(512x1024) * xt (+bias, /1024). Same structure.
// grid (128 n-tiles, 2 m-tiles), block 512. K-tiles = 32.
// ---------------------------------------------------------------------------
__global__ __launch_bounds__(512, 2) void gemm2(
    const f16* __restrict__ A2h, const f16* __restrict__ A2l,
    const f16* __restrict__ Bh, const f16* __restrict__ Bl,
    const float* __restrict__ bias, float* __restrict__ preds) {
  __shared__ __align__(16) f16 S[65536];
  const int tid = threadIdx.x;
  const int l = tid & 63, w = tid >> 6;
  const int wm = w >> 2, wn = w & 3;
  const int rho = l & 15, cq = l >> 4;
  const int sc = (cq - rho) & 3;
  const int roff = (rho + 16 * ((cq + rho) & 3)) * 8;
  const int nt = blockIdx.x, mt = blockIdx.y;
  const int n0 = nt * 256, co0 = mt * 256;

  const int a0u = (w & 3) + (w >> 2) * 8;
  const int a1u = a0u + 4;
  const int b0u = (w & 1) + (w >> 1) * 4;
  const int b1u = b0u + 2;

  const long aS0 = (long)(co0 + a0u * 16 + rho) * 1024 + sc * 8;
  const long aS1 = (long)(co0 + a1u * 16 + rho) * 1024 + sc * 8;
  const long bS0 = (long)(n0 + b0u * 16 + rho) * 1024 + sc * 8;
  const long bS1 = (long)(n0 + b1u * 16 + rho) * 1024 + sc * 8;

  f32x4 acc[8][4] = {};
  f16x8 ah[4], al[4], bh0[2], bl0[2], bh1[2], bl1[2];

  gload16(A2h + aS0, &S[R_AH + a0u * 512]);
  gload16(A2l + aS0, &S[R_AL + a0u * 512]);
  gload16(Bh + bS0, &S[R_BH + b0u * 512]);
  gload16(Bl + bS0, &S[R_BL + b0u * 512]);
  gload16(A2h + aS1, &S[R_AH + a1u * 512]);
  gload16(A2l + aS1, &S[R_AL + a1u * 512]);
  gload16(Bh + bS1, &S[R_BH + b1u * 512]);
  gload16(Bl + bS1, &S[R_BL + b1u * 512]);
  ASM_VMCNT(4);
  SBAR();

  for (int t = 0; t < 32; ++t) {
    const int cb = (t & 1) << 13;
    const int nb = 8192 - cb;
    const long kn = (long)((t < 31) ? t + 1 : t) * 32;  // clamped prefetch

    // ---- P0 ----
#pragma unroll
    for (int mf = 0; mf < 4; ++mf) {
      const int u = wm * 8 + mf;
      ah[mf] = *(const f16x8*)&S[R_AH + cb + u * 512 + roff];
      al[mf] = *(const f16x8*)&S[R_AL + cb + u * 512 + roff];
    }
#pragma unroll
    for (int nf = 0; nf < 2; ++nf) {
      const int u = wn * 4 + nf;
      bh0[nf] = *(const f16x8*)&S[R_BH + cb + u * 512 + roff];
      bl0[nf] = *(const f16x8*)&S[R_BL + cb + u * 512 + roff];
    }
    gload16(A2h + aS0 + kn, &S[R_AH + nb + a0u * 512]);
    gload16(A2l + aS0 + kn, &S[R_AL + nb + a0u * 512]);
    ASM_VMCNT(2);
    SBAR();
    __builtin_amdgcn_s_setprio(1);
#pragma unroll
    for (int mf = 0; mf < 4; ++mf)
#pragma unroll
      for (int nf = 0; nf < 2; ++nf) {
        acc[mf][nf] = MFMA(ah[mf], bh0[nf], acc[mf][nf]);
        acc[mf][nf] = MFMA(ah[mf], bl0[nf], acc[mf][nf]);
        acc[mf][nf] = MFMA(al[mf], bh0[nf], acc[mf][nf]);
      }
    __builtin_amdgcn_s_setprio(0);

    // ---- P1 ----
#pragma unroll
    for (int nf = 0; nf < 2; ++nf) {
      const int u = wn * 4 + 2 + nf;
      bh1[nf] = *(const f16x8*)&S[R_BH + cb + u * 512 + roff];
      bl1[nf] = *(const f16x8*)&S[R_BL + cb + u * 512 + roff];
    }
    gload16(Bh + bS0 + kn, &S[R_BH + nb + b0u * 512]);
    gload16(Bl + bS0 + kn, &S[R_BL + nb + b0u * 512]);
    SBAR();
    __builtin_amdgcn_s_setprio(1);
#pragma unroll
    for (int mf = 0; mf < 4; ++mf)
#pragma unroll
      for (int nf = 0; nf < 2; ++nf) {
        acc[mf][2 + nf] = MFMA(ah[mf], bh1[nf], acc[mf][2 + nf]);
        acc[mf][2 + nf] = MFMA(ah[mf], bl1[nf], acc[mf][2 + nf]);
        acc[mf][2 + nf] = MFMA(al[mf], bh1[nf], acc[mf][2 + nf]);
      }
    __builtin_amdgcn_s_setprio(0);

    // ---- P2 ----
#pragma unroll
    for (int mf = 0; mf < 4; ++mf) {
      const int u = wm * 8 + 4 + mf;
      ah[mf] = *(const f16x8*)&S[R_AH + cb + u * 512 + roff];
      al[mf] = *(const f16x8*)&S[R_AL + cb + u * 512 + roff];
    }
    gload16(A2h + aS1 + kn, &S[R_AH + nb + a1u * 512]);
    gload16(A2l + aS1 + kn, &S[R_AL + nb + a1u * 512]);
    SBAR();
    __builtin_amdgcn_s_setprio(1);
#pragma unroll
    for (int mf = 0; mf < 4; ++mf)
#pragma unroll
      for (int nf = 0; nf < 2; ++nf) {
        acc[4 + mf][nf] = MFMA(ah[mf], bh0[nf], acc[4 + mf][nf]);
        acc[4 + mf][nf] = MFMA(ah[mf], bl0[nf], acc[4 + mf][nf]);
        acc[4 + mf][nf] = MFMA(al[mf], bh0[nf], acc[4 + mf][nf]);
      }
    __builtin_amdgcn_s_setprio(0);

    // ---- P3 ----
    gload16(Bh + bS1 + kn, &S[R_BH + nb + b1u * 512]);
    gload16(Bl + bS1 + kn, &S[R_BL + nb + b1u * 512]);
    ASM_VMCNT(4);
    SBAR();
    __builtin_amdgcn_s_setprio(1);
#pragma unroll
    for (int mf = 0; mf < 4; ++mf)
#pragma unroll
      for (int nf = 0; nf < 2; ++nf) {
        acc[4 + mf][2 + nf] = MFMA(ah[mf], bh1[nf], acc[4 + mf][2 + nf]);
        acc[4 + mf][2 + nf] = MFMA(ah[mf], bl1[nf], acc[4 + mf][2 + nf]);
        acc[4 + mf][2 + nf] = MFMA(al[mf], bh1[nf], acc[4 + mf][2 + nf]);
      }
    __builtin_amdgcn_s_setprio(0);
  }

#pragma unroll
  for (int am = 0; am < 8; ++am) {
    const int cob = co0 + wm * 128 + am * 16 + cq * 4;
    const float4 bi = *(const float4*)(bias + cob);
#pragma unroll
    for (int an = 0; an < 4; ++an) {
      const int col = n0 + wn * 64 + an * 16 + rho;
      f32x4 a = acc[am][an];
      float4 o;
      o.x = a[0] * 9.765625e-4f + bi.x;
      o.y = a[1] * 9.765625e-4f + bi.y;
      o.z = a[2] * 9.765625e-4f + bi.z;
      o.w = a[3] * 9.765625e-4f + bi.w;
      *(float4*)(preds + (long)col * 512 + cob) = o;
    }
  }
}

// ---------------------------------------------------------------------------
__global__ __launch_bounds__(256) void decode(const float* __restrict__ preds,
                                              float* __restrict__ out) {
  const int t = blockIdx.x * 256 + threadIdx.x;  // < 163840
  const int b = t / 5120, rem = t % 5120, pos = rem / 5, a = rem % 5;
  const int n = (b << 10) + pos;
  const float* p = preds + (long)n * 512 + a * 85;

  float tx = p[0], ty = p[1], tw = p[2], th = p[3], to = p[4];
  float mx = p[5];
  int arg = 0;
  for (int i = 1; i < 80; ++i) {
    float v = p[5 + i];
    if (v > mx) { mx = v; arg = i; }
  }
  float sum = 0.f;
  for (int i = 0; i < 80; ++i) sum += expf(p[5 + i] - mx);

  float obj = 1.f / (1.f + expf(-to));
  float score = obj / sum;
  float bx = 1.f / (1.f + expf(-tx));
  float by = 1.f / (1.f + expf(-ty));
  float bw = expf(fminf(tw, 8.f));
  float bh2 = expf(fminf(th, 8.f));
  float cx = (bx + (float)(pos & 31)) * 32.f;
  float cy = (by + (float)(pos >> 5)) * 32.f;
  float pw = c_AW[a] * bw;
  float ph = c_AH_[a] * bh2;
  float x1 = fminf(fmaxf(cx - 0.5f * pw, 0.f), 1023.f);
  float y1 = fminf(fmaxf(cy - 0.5f * ph, 0.f), 1023.f);
  float x2 = fminf(fmaxf(cx + 0.5f * pw, 0.f), 1023.f);
  float y2 = fminf(fmaxf(cy + 0.5f * ph, 0.f), 1023.f);

  const long o = ((long)b * 5120 + pos * 5 + a) * 5;
  out[o + 0] = x1;
  out[o + 1] = y1;
  out[o + 2] = x2;
  out[o + 3] = y2;
  out[o + 4] = score;
  out[819200 + (long)b * 5120 + pos * 5 + a] = (float)arg;
}

// ---------------------------------------------------------------------------
// workspace layout (bytes):
//   0          fph  [32][34][34][512] f16   37,879,808
//   37879808   fpl                          37,879,808
//   75759616   A1h  [1024][4608] f16         9,437,184
//   85196800   A1l                           9,437,184
//   94633984   A2h  [512][1024] f16          1,048,576
//   95682560   A2l                           1,048,576
//   96731136   scale f32[1024]                   4,096
//   96735232   shift f32[1024]                   4,096
//   96739328   bias  f32[512]                    2,048
//   96741376   xth  [32768][1024] f16       67,108,864
//   163850240  xtl                          67,108,864
//   total 230,959,104;  preds f32[32768][512] aliases offset 0
// ---------------------------------------------------------------------------
extern "C" void kernel_launch(void* const* d_in, const int* in_sizes, int n_in,
                              void* d_out, int out_size, void* d_ws, size_t ws_size,
                              hipStream_t stream) {
  (void)in_sizes; (void)n_in; (void)out_size; (void)ws_size;
  const float* features = (const float*)d_in[0];
  const float* conv1_w = (const float*)d_in[1];
  const float* bn_g = (const float*)d_in[2];
  const float* bn_b = (const float*)d_in[3];
  const float* bn_m = (const float*)d_in[4];
  const float* bn_v = (const float*)d_in[5];
  const float* conv2_w = (const float*)d_in[6];
  const float* conv2_b = (const float*)d_in[7];
  float* out = (float*)d_out;
  char* ws = (char*)d_ws;

  f16* fph = (f16*)(ws + 0);
  f16* fpl = (f16*)(ws + 37879808L);
  f16* A1h = (f16*)(ws + 75759616L);
  f16* A1l = (f16*)(ws + 85196800L);
  f16* A2h = (f16*)(ws + 94633984L);
  f16* A2l = (f16*)(ws + 95682560L);
  float* scale = (float*)(ws + 96731136L);
  float* shift = (float*)(ws + 96735232L);
  float* bias = (float*)(ws + 96739328L);
  f16* xth = (f16*)(ws + 96741376L);
  f16* xtl = (f16*)(ws + 163850240L);
  float* preds = (float*)(ws + 0);  // alias: fp dead after gemm1

  hipMemsetAsync(ws, 0, 75759616L, stream);  // zero padded feature rings
  prep_misc<<<1, 1024, 0, stream>>>(bn_g, bn_b, bn_m, bn_v, conv2_b, scale, shift, bias);
  prep_w1<<<dim3(1024, 18), 256, 0, stream>>>(conv1_w, A1h, A1l);
  prep_w2<<<dim3(512, 4), 256, 0, stream>>>(conv2_w, A2h, A2l);
  prep_feat<<<dim3(32, 32), 256, 0, stream>>>(features, fph, fpl);
  gemm1<<<dim3(128, 4), 512, 0, stream>>>(A1h, A1l, fph, fpl, scale, shift, xth, xtl);
  gemm2<<<dim3(128, 2), 512, 0, stream>>>(A2h, A2l, xth, xtl, bias, preds);
  decode<<<640, 256, 0, stream>>>(preds, out);
}